// Round 15
// baseline (410.885 us; speedup 1.0000x reference)
//
#include <hip/hip_runtime.h>

#define DI __device__ __forceinline__

typedef __attribute__((ext_vector_type(8))) short bf16x8;  // 8 bf16 bit-patterns
typedef __attribute__((ext_vector_type(4))) short s16x4;
typedef __attribute__((ext_vector_type(4))) float f32x4;

DI short f2bs(float x){ unsigned u = __float_as_uint(x);
  return (short)((u + 0x7FFF + ((u >> 16) & 1)) >> 16); }          // RNE f32->bf16
DI float bs2f(short s){ return __uint_as_float(((unsigned)(unsigned short)s) << 16); }
DI f32x4 MFMA(bf16x8 a, bf16x8 b, f32x4 c){
  return __builtin_amdgcn_mfma_f32_16x16x32_bf16(a, b, c, 0, 0, 0);
}

// Problem constants
constexpr int NP   = 8192;
constexpr int NTOT = 16384;     // B*NP (reference flattens batch)
constexpr int M    = 4096;      // B*M_ROIS
constexpr int C    = 128;
constexpr int O    = 256;
constexpr int NS   = 32;
constexpr int H    = 4;
constexpr int KP   = 160;       // padded K: 0..127 feats, 128..130 gx, rest 0
constexpr int GFS  = 168;       // gf LDS row stride (shorts); 336B rows, 16B-aligned
constexpr int VS   = 264;       // [n][o] v-staging row stride (shorts)
constexpr int NSP  = 34;        // [o][n] transposed row stride (shorts); dword stride 17 -> conflict-free
constexpr float BNS = 0.99999500003749969f;  // 1/sqrt(1+1e-5)

// ---------------- K0: front — transpose + pack + ball query, ONE dispatch ----------------
// blocks 0..255: features (B,C,NP) f32 -> fT bf16 [B*NP][C]
// blocks 256..511: weight packing (65536 threads, full O*O coverage)
// blocks 512..4607: ball query (4 waves per query, raw xyz loads — no prep dependency)
__global__ __launch_bounds__(256) void k_front(
    const float* __restrict__ feat,
    const float* __restrict__ kw, const float* __restrict__ v1w,
    const float* __restrict__ v2w,
    const float* __restrict__ vcw, const float* __restrict__ qcw,
    const float* __restrict__ kcw, const float* __restrict__ qkcw,
    const float* __restrict__ cw1, const float* __restrict__ rw1,
    const float* __restrict__ xyz, const float* __restrict__ nxyz,
    short* __restrict__ fT,
    short* __restrict__ keyP, short* __restrict__ v1P,
    short* __restrict__ v2b,
    short* __restrict__ gw,            // 4 x O x O bf16 (vc,qc,kc,qkc)
    short* __restrict__ cw1b, short* __restrict__ rw1b,
    int* __restrict__ idxo, float* __restrict__ gxo)
{
#pragma clang fp contract(off)
  __shared__ __align__(16) float tile[128][65];
  int blk = blockIdx.x;
  int t = threadIdx.x;
  if(blk < 256){
    int b  = blk >> 7;
    int n0 = (blk & 127) << 6;
    int nn = t & 63, c4 = t >> 6;
    const float* src = feat + (size_t)b * C * NP;
    for(int i = 0; i < 32; i++){
      int c = c4 * 32 + i;
      tile[c][nn] = src[(size_t)c * NP + n0 + nn];
    }
    __syncthreads();
    int c2 = t & 127, nb = t >> 7;
    for(int j = 0; j < 32; j++){
      int n = nb + j * 2;
      fT[((size_t)(b * NP + n0 + n)) * C + c2] = f2bs(tile[c2][n]);
    }
    return;
  }
  if(blk < 512){
    int i = (blk - 256) * 256 + t;     // 0 .. 65535
    if(i < O * KP){
      int o = i / KP, k = i % KP;
      float a = 0.0f, b = 0.0f;
      if(k < 128){ a = kw[o*131 + 3 + k]; b = v1w[o*131 + 3 + k]; }
      else if(k < 131){ a = kw[o*131 + (k - 128)]; b = v1w[o*131 + (k - 128)]; }
      keyP[i] = f2bs(a);
      v1P[i]  = f2bs(b);
    }
    if(i < O * O){
      v2b[i] = f2bs(v2w[i]);
      gw[0*O*O + i] = f2bs(vcw[i]);
      gw[1*O*O + i] = f2bs(qcw[i]);
      gw[2*O*O + i] = f2bs(kcw[i]);
      gw[3*O*O + i] = f2bs(qkcw[i]);
    }
    if(i < (O/2) * O){
      cw1b[i] = f2bs(cw1[i]);
      rw1b[i] = f2bs(rw1[i]);
    }
    return;
  }
  // ---- ball query: m = blk - 512 ----
  int m = blk - 512;
  int w = t >> 6, lane = t & 63;
  float qx = nxyz[m*3+0], qy = nxyz[m*3+1], qz = nxyz[m*3+2];
  int* sel  = (int*)&tile[0][0];     // overlay: NS ints
  int* wcnt = sel + NS;              // [2][4]
  int cnt = 0;
  int par = 0;
  for(int base = 0; base < NTOT; base += 256){
    int p = base + t;
    float px = xyz[p*3+0], py = xyz[p*3+1], pz = xyz[p*3+2];
    float dx = qx - px, dy = qy - py, dz = qz - pz;
    float d2 = dx*dx + dy*dy;    // numpy order: (x^2+y^2)+z^2, no contraction
    d2 = d2 + dz*dz;
    bool pred = d2 < 2.56f;
    unsigned long long bal = __ballot(pred);
    if(lane == 0) wcnt[par*4 + w] = __popcll(bal);
    __syncthreads();
    int c0 = wcnt[par*4+0], c1 = wcnt[par*4+1], c2 = wcnt[par*4+2], c3 = wcnt[par*4+3];
    int off = cnt + ((w > 0) ? c0 : 0) + ((w > 1) ? c1 : 0) + ((w > 2) ? c2 : 0);
    if(pred){
      int pos = off + __popcll(bal & ((1ull << lane) - 1ull));
      if(pos < NS) sel[pos] = p;
    }
    cnt += c0 + c1 + c2 + c3;
    par ^= 1;
    if(cnt >= NS) break;         // block-uniform
  }
  __syncthreads();               // publish sel[] writes from the final iteration
  if(t < NS){
    int s = 0;
    if(cnt > 0) s = (t < cnt) ? sel[t] : sel[0];  // pad with first; empty -> 0
    idxo[m*NS + t] = s;
    gxo[(m*NS+t)*3+0] = xyz[s*3+0] - qx;
    gxo[(m*NS+t)*3+1] = xyz[s*3+1] - qy;
    gxo[(m*NS+t)*3+2] = xyz[s*3+2] - qz;
  }
}

// ---------------- K2: fused convs + means; outputs key/val TRANSPOSED [o][n] ----------------
// r14 structure (verified best: 165us, FETCH 26MB, WRITE 170MB).
__global__ __launch_bounds__(256, 5) void k_conv(
    const short* __restrict__ fT,
    const short* __restrict__ keyP, const short* __restrict__ v1P,
    const short* __restrict__ v2b,
    const float* __restrict__ posw,
    const float* __restrict__ g1, const float* __restrict__ b1,
    const float* __restrict__ g2, const float* __restrict__ b2,
    const int* __restrict__ idxw, const float* __restrict__ gxw,
    short* __restrict__ keyT, short* __restrict__ valT,
    short* __restrict__ mPos, short* __restrict__ mKey, short* __restrict__ mPK,
    int q0)
{
  int lq = blockIdx.x, q = q0 + lq, t = threadIdx.x;
  int w = t >> 6, l = t & 63;
  int col = l & 15, kq = l >> 4;
  int ro = w * 64;
  __shared__ __align__(16) short gf[NS * GFS];    // 10752 B
  __shared__ __align__(16) short buf[O * NSP];    // 17408 B (>= NS*VS = 16896)
  __shared__ float gxs[NS * 4];                   // 512 B
  __shared__ int  sel[NS];                        // 128 B   total 28800 B -> 5 blocks/CU
  if(t < NS){
    sel[t] = idxw[q*NS + t];
    gxs[t*4+0] = gxw[(q*NS+t)*3+0];
    gxs[t*4+1] = gxw[(q*NS+t)*3+1];
    gxs[t*4+2] = gxw[(q*NS+t)*3+2];
    gxs[t*4+3] = 0.0f;
  }
  __syncthreads();
  // gather features: 16B/lane — 16-lane group loads one 256B row (2 iters vs 8)
  for(int i = 0; i < 2; i++){
    int n = w*8 + i*4 + kq;          // kq = l>>4: group index within wave
    int p = sel[n];
    *(bf16x8*)&gf[n*GFS + col*8] = *(const bf16x8*)(fT + (size_t)p * C + col*8);
  }
  // gx channels 128..130 + zero pad to 159
  {
    int n = t & 31, kk = (t >> 5) * 4;
    for(int j = 0; j < 4; j++){
      int k = kk + j;
      float v = (k < 3) ? gxs[n*4 + k] : 0.0f;
      gf[n*GFS + 128 + k] = f2bs(v);
    }
  }
  __syncthreads();

  f32x4 acc[4][2];
  const f32x4 vzero = {0.0f, 0.0f, 0.0f, 0.0f};

  // ---- key = relu(W_key @ gf) ----
  for(int mt=0;mt<4;mt++) for(int nt=0;nt<2;nt++) acc[mt][nt] = vzero;
  for(int ks = 0; ks < 5; ks++){
    bf16x8 b0 = *(const bf16x8*)&gf[col*GFS + ks*32 + kq*8];
    bf16x8 b1v = *(const bf16x8*)&gf[(16+col)*GFS + ks*32 + kq*8];
    for(int mt = 0; mt < 4; mt++){
      bf16x8 a = *(const bf16x8*)(keyP + (size_t)(ro + mt*16 + col)*KP + ks*32 + kq*8);
      acc[mt][0] = MFMA(a, b0, acc[mt][0]);
      acc[mt][1] = MFMA(a, b1v, acc[mt][1]);
    }
  }
  // stage key TRANSPOSED buf[o][n]
  for(int mt=0;mt<4;mt++) for(int nt=0;nt<2;nt++)
    for(int r=0;r<4;r++){
      int o = ro + mt*16 + kq*4 + r;
      int n = nt*16 + col;
      buf[o*NSP + n] = f2bs(fmaxf(acc[mt][nt][r], 0.0f));
    }
  // means inline from the still-live key acc; pos recomputed from gxs; bf16 out
  for(int mt=0;mt<4;mt++){
    for(int r=0;r<4;r++){
      int o = ro + mt*16 + kq*4 + r;
      float w0 = posw[o*3+0], w1 = posw[o*3+1], w2 = posw[o*3+2];
      float sp = 0, sk = 0, spk = 0;
      for(int nt=0;nt<2;nt++){
        int n = nt*16 + col;
        float p = fmaxf(w0*gxs[n*4+0] + w1*gxs[n*4+1] + w2*gxs[n*4+2], 0.0f);
        float v = fmaxf(acc[mt][nt][r], 0.0f);
        sp += p; sk += v; spk += p*v;
      }
      for(int msk=1; msk<16; msk<<=1){
        sp += __shfl_xor(sp, msk); sk += __shfl_xor(sk, msk); spk += __shfl_xor(spk, msk);
      }
      if(col == 0){
        mPos[lq*O+o] = f2bs(sp  * 0.03125f);
        mKey[lq*O+o] = f2bs(sk  * 0.03125f);
        mPK [lq*O+o] = f2bs(spk * 0.03125f);
      }
    }
  }
  __syncthreads();
  // keyT global write: thread t streams row o=t (16 conflict-free dword LDS reads)
  {
    uint vv[16];
    #pragma unroll
    for(int j=0;j<16;j++) vv[j] = *(const uint*)&buf[t*NSP + j*2];
    uint4* dst = (uint4*)(keyT + ((size_t)lq*O + t)*NS);
    dst[0] = make_uint4(vv[0],vv[1],vv[2],vv[3]);
    dst[1] = make_uint4(vv[4],vv[5],vv[6],vv[7]);
    dst[2] = make_uint4(vv[8],vv[9],vv[10],vv[11]);
    dst[3] = make_uint4(vv[12],vv[13],vv[14],vv[15]);
  }

  // ---- v = relu(bn1(W_v1 @ gf)) ----
  for(int mt=0;mt<4;mt++) for(int nt=0;nt<2;nt++) acc[mt][nt] = vzero;
  for(int ks = 0; ks < 5; ks++){
    bf16x8 b0 = *(const bf16x8*)&gf[col*GFS + ks*32 + kq*8];
    bf16x8 b1v = *(const bf16x8*)&gf[(16+col)*GFS + ks*32 + kq*8];
    for(int mt = 0; mt < 4; mt++){
      bf16x8 a = *(const bf16x8*)(v1P + (size_t)(ro + mt*16 + col)*KP + ks*32 + kq*8);
      acc[mt][0] = MFMA(a, b0, acc[mt][0]);
      acc[mt][1] = MFMA(a, b1v, acc[mt][1]);
    }
  }
  __syncthreads();      // keyT row reads of buf complete; safe to overwrite as [n][VS]
  for(int mt=0;mt<4;mt++){
    int o0 = ro + mt*16 + kq*4;
    float gg[4], bb[4];
    for(int r=0;r<4;r++){ gg[r] = g1[o0+r]; bb[r] = b1[o0+r]; }
    for(int nt=0;nt<2;nt++){
      s16x4 pk;
      for(int r=0;r<4;r++)
        pk[r] = f2bs(fmaxf(gg[r]*(acc[mt][nt][r] * BNS) + bb[r], 0.0f));
      int n = nt*16 + col;
      *(s16x4*)&buf[n*VS + o0] = pk;
    }
  }
  __syncthreads();

  // ---- val = relu(bn2(W_v2 @ v)) ----
  for(int mt=0;mt<4;mt++) for(int nt=0;nt<2;nt++) acc[mt][nt] = vzero;
  for(int ks = 0; ks < 8; ks++){
    bf16x8 b0 = *(const bf16x8*)&buf[col*VS + ks*32 + kq*8];
    bf16x8 b1v = *(const bf16x8*)&buf[(16+col)*VS + ks*32 + kq*8];
    for(int mt = 0; mt < 4; mt++){
      bf16x8 a = *(const bf16x8*)(v2b + (size_t)(ro + mt*16 + col)*O + ks*32 + kq*8);
      acc[mt][0] = MFMA(a, b0, acc[mt][0]);
      acc[mt][1] = MFMA(a, b1v, acc[mt][1]);
    }
  }
  __syncthreads();      // v2 reads of buf complete; stage val TRANSPOSED
  for(int mt=0;mt<4;mt++){
    int o0 = ro + mt*16 + kq*4;
    float gg[4], bb[4];
    for(int r=0;r<4;r++){ gg[r] = g2[o0+r]; bb[r] = b2[o0+r]; }
    for(int nt=0;nt<2;nt++){
      int n = nt*16 + col;
      for(int r=0;r<4;r++)
        buf[(o0+r)*NSP + n] = f2bs(fmaxf(gg[r]*(acc[mt][nt][r] * BNS) + bb[r], 0.0f));
    }
  }
  __syncthreads();
  // valT global write
  {
    uint vv[16];
    #pragma unroll
    for(int j=0;j<16;j++) vv[j] = *(const uint*)&buf[t*NSP + j*2];
    uint4* dst = (uint4*)(valT + ((size_t)lq*O + t)*NS);
    dst[0] = make_uint4(vv[0],vv[1],vv[2],vv[3]);
    dst[1] = make_uint4(vv[4],vv[5],vv[6],vv[7]);
    dst[2] = make_uint4(vv[8],vv[9],vv[10],vv[11]);
    dst[3] = make_uint4(vv[12],vv[13],vv[14],vv[15]);
  }
}

// ---------------- K3: channel gates, batched MFMA, bf16 means in ----------------
__global__ __launch_bounds__(256) void k_gates(
    const short* __restrict__ mPos, const short* __restrict__ mKey,
    const short* __restrict__ mPK, const short* __restrict__ gw,
    float* __restrict__ gates)
{
  int t = threadIdx.x, w = t >> 6, l = t & 63, col = l & 15, kq = l >> 4;
  int lq0 = blockIdx.x * 16;
  const short* A  = (w < 2) ? mPos : ((w == 2) ? mKey : mPK);
  const short* Wg = gw + (size_t)w * O * O;
  f32x4 acc[16];
  const f32x4 vzero = {0.0f,0.0f,0.0f,0.0f};
  for(int i=0;i<16;i++) acc[i] = vzero;
  for(int ks = 0; ks < 8; ks++){
    bf16x8 av = *(const bf16x8*)(A + (size_t)(lq0 + col)*O + ks*32 + kq*8);
    for(int nt = 0; nt < 16; nt++){
      bf16x8 bv = *(const bf16x8*)(Wg + (size_t)(nt*16 + col)*O + ks*32 + kq*8);
      acc[nt] = MFMA(av, bv, acc[nt]);
    }
  }
  for(int nt=0;nt<16;nt++) for(int r=0;r<4;r++){
    int lqq = lq0 + kq*4 + r;
    int oo = nt*16 + col;
    gates[((size_t)lqq*4 + w)*O + oo] = 1.0f / (1.0f + expf(-acc[nt][r]));
  }
}

// ---------------- K4: attention + new_features + cls/reg gating (fused tail) ----------------
__global__ __launch_bounds__(256) void k_attnf(
    const short* __restrict__ keyT, const short* __restrict__ valT,
    const float* __restrict__ gxw, const float* __restrict__ posw,
    const float* __restrict__ attw, const float* __restrict__ gates,
    const short* __restrict__ cw1b, const float* __restrict__ cb1,
    const float* __restrict__ cw2, const float* __restrict__ cb2,
    const short* __restrict__ rw1b, const float* __restrict__ rb1,
    const float* __restrict__ rw2, const float* __restrict__ rb2,
    float* __restrict__ outNF, float* __restrict__ outC, float* __restrict__ outR,
    int q0)
{
  int lq = blockIdx.x, q = q0 + lq, t = threadIdx.x;
  __shared__ short embL[O * NSP];      // 17408 B (bf16 emb, [o][n]); later overlaid by nfL
  __shared__ float attnL[H * NS];      // 512 B
  __shared__ float gxs[NS * 3];        // 384 B
  __shared__ float partial[256];       // 1024 B (scores, then MLP partials)
  __shared__ float sGate[2];           // 8 B     total ~19.3 KB
  float* nfL = (float*)embL;           // overlay: nf[256] f32 (emb dead by then)
  if(t < 96) gxs[t] = gxw[q*96 + t];
  float vc  = gates[((size_t)lq*4 + 0)*O + t];
  float qc  = gates[((size_t)lq*4 + 1)*O + t];
  float kc  = gates[((size_t)lq*4 + 2)*O + t];
  float qkc = gates[((size_t)lq*4 + 3)*O + t];
  float pw0 = posw[t*3+0], pw1 = posw[t*3+1], pw2 = posw[t*3+2];
  __syncthreads();
  float posr[NS];
  #pragma unroll
  for(int n = 0; n < NS; n++)
    posr[n] = fmaxf(pw0*gxs[n*3] + pw1*gxs[n*3+1] + pw2*gxs[n*3+2], 0.0f);
  // vectorized key read (64B contiguous per thread) -> emb bf16 -> LDS row t
  {
    const short* kp = keyT + ((size_t)lq*O + t)*NS;
    #pragma unroll
    for(int g = 0; g < 4; g++){
      bf16x8 kg = *(const bf16x8*)(kp + g*8);
      #pragma unroll
      for(int jj = 0; jj < 4; jj++){
        int n0 = g*8 + jj*2;
        float kA = bs2f(kg[jj*2]),   kB = bs2f(kg[jj*2+1]);
        float eA = posr[n0]*qc   + kA*kc + posr[n0]*kA*qkc;
        float eB = posr[n0+1]*qc + kB*kc + posr[n0+1]*kB*qkc;
        unsigned pk = (unsigned)(unsigned short)f2bs(eA)
                    | ((unsigned)(unsigned short)f2bs(eB) << 16);
        *(unsigned*)&embL[t*NSP + n0] = pk;     // 4B aligned (n0 even)
      }
    }
  }
  __syncthreads();
  // score partial dot: 256 threads = 2 halves x (4 h x 32 n)
  {
    int idx = t & 127, h = idx >> 5, n = idx & 31, half = t >> 7;
    const float* aw = attw + h*O + half*128;
    const short* eb = embL + (size_t)half*128*NSP + n;
    float s0=0, s1=0, s2=0, s3=0;
    for(int o = 0; o < 128; o += 4){
      s0 += aw[o+0] * bs2f(eb[(o+0)*NSP]);
      s1 += aw[o+1] * bs2f(eb[(o+1)*NSP]);
      s2 += aw[o+2] * bs2f(eb[(o+2)*NSP]);
      s3 += aw[o+3] * bs2f(eb[(o+3)*NSP]);
    }
    partial[t] = (s0 + s1) + (s2 + s3);
  }
  __syncthreads();
  if(t < 128){
    int h = t >> 5, n = t & 31;
    float s = partial[t] + partial[t + 128];
    float mx = s;
    for(int msk=1; msk<32; msk<<=1) mx = fmaxf(mx, __shfl_xor(mx, msk));
    float e = expf(s - mx);
    float sum = e;
    for(int msk=1; msk<32; msk<<=1) sum += __shfl_xor(sum, msk);
    attnL[h*NS + n] = e / sum;
  }
  __syncthreads();
  // nf: vectorized val read (64B contiguous per thread)
  float nft;
  {
    const short* vp = valT + ((size_t)lq*O + t)*NS;
    int hh = t >> 6;
    float nf = 0;
    #pragma unroll
    for(int g = 0; g < 4; g++){
      bf16x8 vg = *(const bf16x8*)(vp + g*8);
      #pragma unroll
      for(int j = 0; j < 8; j++){
        int n = g*8 + j;
        nf += (bs2f(vg[j]) + posr[n]*vc) * attnL[hh*NS + n];
      }
    }
    nft = nf;
    outNF[(size_t)q*O + t] = nft;
  }
  __syncthreads();     // emb reads done -> safe to overlay nfL
  nfL[t] = nft;
  __syncthreads();
  // ---- cls/reg gating MLPs: 128 cls hidden (t<128) + 128 reg hidden (t>=128) ----
  {
    int j = t & 127;
    const short* W1 = (t < 128) ? cw1b : rw1b;
    float bias = (t < 128) ? cb1[j] : rb1[j];
    float w2v  = (t < 128) ? cw2[j] : rw2[j];
    const short* row = W1 + (size_t)j * O;
    float h = 0;
    for(int c8 = 0; c8 < 32; c8++){
      bf16x8 wv = *(const bf16x8*)(row + c8*8);
      #pragma unroll
      for(int e = 0; e < 8; e++) h += bs2f(wv[e]) * nfL[c8*8 + e];
    }
    partial[t] = fmaxf(h + bias, 0.0f) * w2v;
  }
  __syncthreads();
  if(t < 64){
    float s = partial[t] + partial[t + 64];
    for(int msk=1; msk<64; msk<<=1) s += __shfl_xor(s, msk);
    if(t == 0) sGate[0] = 1.0f / (1.0f + expf(-(s + cb2[0])));
  } else if(t >= 128 && t < 192){
    float s = partial[t] + partial[t + 64];
    for(int msk=1; msk<64; msk<<=1) s += __shfl_xor(s, msk);
    if(t == 128) sGate[1] = 1.0f / (1.0f + expf(-(s + rb2[0])));
  }
  __syncthreads();
  outC[(size_t)q*O + t] = nft * sGate[0];
  outR[(size_t)q*O + t] = nft * sGate[1];
}

extern "C" void kernel_launch(void* const* d_in, const int* in_sizes, int n_in,
                              void* d_out, int out_size, void* d_ws, size_t ws_size,
                              hipStream_t stream)
{
  const float* xyz  = (const float*)d_in[0];
  const float* nxyz = (const float*)d_in[1];
  const float* feat = (const float*)d_in[2];
  const float* posw = (const float*)d_in[3];
  const float* keyw = (const float*)d_in[4];
  const float* v1w  = (const float*)d_in[5];
  const float* bn1g = (const float*)d_in[6];
  const float* bn1b = (const float*)d_in[7];
  const float* v2w  = (const float*)d_in[8];
  const float* bn2g = (const float*)d_in[9];
  const float* bn2b = (const float*)d_in[10];
  const float* attw = (const float*)d_in[11];
  const float* kcw  = (const float*)d_in[12];
  const float* qcw  = (const float*)d_in[13];
  const float* qkcw = (const float*)d_in[14];
  const float* vcw  = (const float*)d_in[15];
  const float* cw1  = (const float*)d_in[16];
  const float* cb1  = (const float*)d_in[17];
  const float* cw2  = (const float*)d_in[18];
  const float* cb2  = (const float*)d_in[19];
  const float* rw1  = (const float*)d_in[20];
  const float* rb1  = (const float*)d_in[21];
  const float* rw2  = (const float*)d_in[22];
  const float* rb2  = (const float*)d_in[23];

  char* p = (char*)d_ws;
  auto alloc = [&](size_t bytes){ char* r = p; p += (bytes + 255) & ~size_t(255); return r; };
  short* fT    = (short*)alloc((size_t)NTOT*C*2);
  short* keyP  = (short*)alloc((size_t)O*KP*2);
  short* v1P   = (short*)alloc((size_t)O*KP*2);
  short* v2b   = (short*)alloc((size_t)O*O*2);
  short* gw    = (short*)alloc((size_t)4*O*O*2);
  short* cw1b  = (short*)alloc((size_t)(O/2)*O*2);
  short* rw1b  = (short*)alloc((size_t)(O/2)*O*2);
  int*   idxw  = (int*)  alloc((size_t)M*NS*4);
  float* gxw   = (float*)alloc((size_t)M*NS*3*4);
  short* keyT  = (short*)alloc((size_t)M*O*NS*2);
  short* valT  = (short*)alloc((size_t)M*O*NS*2);
  short* mPos  = (short*)alloc((size_t)M*O*2);
  short* mKey  = (short*)alloc((size_t)M*O*2);
  short* mPK   = (short*)alloc((size_t)M*O*2);
  float* gates = (float*)alloc((size_t)M*4*O*4);

  float* outNF = (float*)d_out;
  float* outC  = outNF + (size_t)M*O;
  float* outR  = outC  + (size_t)M*O;

  k_front <<<512 + M, 256, 0, stream>>>(feat, keyw, v1w, v2w, vcw, qcw, kcw, qkcw,
                                        cw1, rw1, xyz, nxyz,
                                        fT, keyP, v1P, v2b, gw, cw1b, rw1b, idxw, gxw);
  k_conv  <<<M,    256, 0, stream>>>(fT, keyP, v1P, v2b,
                                     posw, bn1g, bn1b, bn2g, bn2b,
                                     idxw, gxw, keyT, valT, mPos, mKey, mPK, 0);
  k_gates <<<M/16, 256, 0, stream>>>(mPos, mKey, mPK, gw, gates);
  k_attnf <<<M,    256, 0, stream>>>(keyT, valT, gxw, posw, attw, gates,
                                     cw1b, cb1, cw2, cb2, rw1b, rb1, rw2, rb2,
                                     outNF, outC, outR, 0);
}

// Round 16
// 357.410 us; speedup vs baseline: 1.1496x; 1.1496x over previous
//
#include <hip/hip_runtime.h>

#define DI __device__ __forceinline__

typedef __attribute__((ext_vector_type(8))) short bf16x8;  // 8 bf16 bit-patterns
typedef __attribute__((ext_vector_type(4))) short s16x4;
typedef __attribute__((ext_vector_type(4))) float f32x4;

DI short f2bs(float x){ unsigned u = __float_as_uint(x);
  return (short)((u + 0x7FFF + ((u >> 16) & 1)) >> 16); }          // RNE f32->bf16
DI float bs2f(short s){ return __uint_as_float(((unsigned)(unsigned short)s) << 16); }
DI f32x4 MFMA(bf16x8 a, bf16x8 b, f32x4 c){
  return __builtin_amdgcn_mfma_f32_16x16x32_bf16(a, b, c, 0, 0, 0);
}

// Problem constants
constexpr int NP   = 8192;
constexpr int NTOT = 16384;     // B*NP (reference flattens batch)
constexpr int M    = 4096;      // B*M_ROIS
constexpr int C    = 128;
constexpr int O    = 256;
constexpr int NS   = 32;
constexpr int H    = 4;
constexpr int KP   = 160;       // padded K: 0..127 feats, 128..130 gx, rest 0
constexpr int GFS  = 168;       // gf LDS row stride (shorts); 336B rows, 16B-aligned
constexpr int VS   = 264;       // [n][o] v-staging row stride (shorts)
constexpr int NSP  = 34;        // [o][n] transposed row stride (shorts); dword stride 17 -> conflict-free
constexpr float BNS = 0.99999500003749969f;  // 1/sqrt(1+1e-5)

// ---------------- K0: merged transpose + weight pack (one dispatch) ----------------
__global__ __launch_bounds__(256) void k_prep(
    const float* __restrict__ feat,
    const float* __restrict__ kw, const float* __restrict__ v1w,
    const float* __restrict__ v2w,
    const float* __restrict__ vcw, const float* __restrict__ qcw,
    const float* __restrict__ kcw, const float* __restrict__ qkcw,
    const float* __restrict__ cw1, const float* __restrict__ rw1,
    const float* __restrict__ xyz, const float* __restrict__ nxyz,
    short* __restrict__ fT,
    short* __restrict__ keyP, short* __restrict__ v1P,
    short* __restrict__ v2b,
    short* __restrict__ gw,            // 4 x O x O bf16 (vc,qc,kc,qkc)
    short* __restrict__ cw1b, short* __restrict__ rw1b,
    float* __restrict__ xyz4, float* __restrict__ nxyz4)
{
  __shared__ float tile[128][65];
  int blk = blockIdx.x;
  int t = threadIdx.x;
  if(blk < 256){
    int b  = blk >> 7;
    int n0 = (blk & 127) << 6;
    int nn = t & 63, c4 = t >> 6;
    const float* src = feat + (size_t)b * C * NP;
    for(int i = 0; i < 32; i++){
      int c = c4 * 32 + i;
      tile[c][nn] = src[(size_t)c * NP + n0 + nn];
    }
    __syncthreads();
    int c2 = t & 127, nb = t >> 7;
    for(int j = 0; j < 32; j++){
      int n = nb + j * 2;
      fT[((size_t)(b * NP + n0 + n)) * C + c2] = f2bs(tile[c2][n]);
    }
    return;
  }
  int i = (blk - 256) * 256 + t;     // 0 .. 65535 over 256 pack blocks
  if(i < O * KP){
    int o = i / KP, k = i % KP;
    float a = 0.0f, b = 0.0f;
    if(k < 128){ a = kw[o*131 + 3 + k]; b = v1w[o*131 + 3 + k]; }
    else if(k < 131){ a = kw[o*131 + (k - 128)]; b = v1w[o*131 + (k - 128)]; }
    keyP[i] = f2bs(a);
    v1P[i]  = f2bs(b);
  }
  if(i < O * O){
    v2b[i] = f2bs(v2w[i]);
    gw[0*O*O + i] = f2bs(vcw[i]);
    gw[1*O*O + i] = f2bs(qcw[i]);
    gw[2*O*O + i] = f2bs(kcw[i]);
    gw[3*O*O + i] = f2bs(qkcw[i]);
  }
  if(i < (O/2) * O){
    cw1b[i] = f2bs(cw1[i]);
    rw1b[i] = f2bs(rw1[i]);
  }
  if(i < NTOT){
    xyz4[i*4+0] = xyz[i*3+0];
    xyz4[i*4+1] = xyz[i*3+1];
    xyz4[i*4+2] = xyz[i*3+2];
    xyz4[i*4+3] = 0.0f;
  }
  if(i < M){
    nxyz4[i*4+0] = nxyz[i*3+0];
    nxyz4[i*4+1] = nxyz[i*3+1];
    nxyz4[i*4+2] = nxyz[i*3+2];
    nxyz4[i*4+3] = 0.0f;
  }
}

// ---------------- K1: ball query, 4 waves per query (exact f32) ----------------
__global__ __launch_bounds__(256) void k_ballq(const float* __restrict__ xyz4,
                                               const float* __restrict__ nxyz4,
                                               int* __restrict__ idxo,
                                               float* __restrict__ gxo){
#pragma clang fp contract(off)
  int m = blockIdx.x;
  int t = threadIdx.x;
  int w = t >> 6, lane = t & 63;
  float qx = nxyz4[m*4+0], qy = nxyz4[m*4+1], qz = nxyz4[m*4+2];
  __shared__ int sel[NS];
  __shared__ int wcnt[2][4];     // double-buffered: 1 barrier per iter
  int cnt = 0;
  int par = 0;
  for(int base = 0; base < NTOT; base += 256){
    int p = base + t;
    const float4 pt = *(const float4*)(xyz4 + (size_t)p*4);
    float dx = qx - pt.x, dy = qy - pt.y, dz = qz - pt.z;
    float d2 = dx*dx + dy*dy;    // numpy order: (x^2+y^2)+z^2, no contraction
    d2 = d2 + dz*dz;
    bool pred = d2 < 2.56f;
    unsigned long long bal = __ballot(pred);
    if(lane == 0) wcnt[par][w] = __popcll(bal);
    __syncthreads();
    int c0 = wcnt[par][0], c1 = wcnt[par][1], c2 = wcnt[par][2], c3 = wcnt[par][3];
    int off = cnt + ((w > 0) ? c0 : 0) + ((w > 1) ? c1 : 0) + ((w > 2) ? c2 : 0);
    if(pred){
      int pos = off + __popcll(bal & ((1ull << lane) - 1ull));
      if(pos < NS) sel[pos] = p;
    }
    cnt += c0 + c1 + c2 + c3;
    par ^= 1;
    if(cnt >= NS) break;         // block-uniform
  }
  __syncthreads();               // publish sel[] writes from the final iteration
  if(t < NS){
    int s = 0;
    if(cnt > 0) s = (t < cnt) ? sel[t] : sel[0];  // pad with first; empty -> 0
    idxo[m*NS + t] = s;
    const float4 ps = *(const float4*)(xyz4 + (size_t)s*4);
    gxo[(m*NS+t)*3+0] = ps.x - qx;
    gxo[(m*NS+t)*3+1] = ps.y - qy;
    gxo[(m*NS+t)*3+2] = ps.z - qz;
  }
}

// ---------------- K2: fused convs + means; outputs key/val TRANSPOSED [o][n] ----------------
// r14 structure (verified best: 165us, FETCH 26MB, WRITE 170MB) + 16B/lane gather.
__global__ __launch_bounds__(256, 5) void k_conv(
    const short* __restrict__ fT,
    const short* __restrict__ keyP, const short* __restrict__ v1P,
    const short* __restrict__ v2b,
    const float* __restrict__ posw,
    const float* __restrict__ g1, const float* __restrict__ b1,
    const float* __restrict__ g2, const float* __restrict__ b2,
    const int* __restrict__ idxw, const float* __restrict__ gxw,
    short* __restrict__ keyT, short* __restrict__ valT,
    short* __restrict__ mPos, short* __restrict__ mKey, short* __restrict__ mPK,
    int q0)
{
  int lq = blockIdx.x, q = q0 + lq, t = threadIdx.x;
  int w = t >> 6, l = t & 63;
  int col = l & 15, kq = l >> 4;
  int ro = w * 64;
  __shared__ __align__(16) short gf[NS * GFS];    // 10752 B
  __shared__ __align__(16) short buf[O * NSP];    // 17408 B (>= NS*VS = 16896)
  __shared__ float gxs[NS * 4];                   // 512 B
  __shared__ int  sel[NS];                        // 128 B   total 28800 B -> 5 blocks/CU
  if(t < NS){
    sel[t] = idxw[q*NS + t];
    gxs[t*4+0] = gxw[(q*NS+t)*3+0];
    gxs[t*4+1] = gxw[(q*NS+t)*3+1];
    gxs[t*4+2] = gxw[(q*NS+t)*3+2];
    gxs[t*4+3] = 0.0f;
  }
  __syncthreads();
  // gather features: 16B/lane — 16-lane group loads one 256B row (2 iters vs 8)
  for(int i = 0; i < 2; i++){
    int n = w*8 + i*4 + kq;          // kq = l>>4: group index within wave
    int p = sel[n];
    *(bf16x8*)&gf[n*GFS + col*8] = *(const bf16x8*)(fT + (size_t)p * C + col*8);
  }
  // gx channels 128..130 + zero pad to 159
  {
    int n = t & 31, kk = (t >> 5) * 4;
    for(int j = 0; j < 4; j++){
      int k = kk + j;
      float v = (k < 3) ? gxs[n*4 + k] : 0.0f;
      gf[n*GFS + 128 + k] = f2bs(v);
    }
  }
  __syncthreads();

  f32x4 acc[4][2];
  const f32x4 vzero = {0.0f, 0.0f, 0.0f, 0.0f};

  // ---- key = relu(W_key @ gf) ----
  for(int mt=0;mt<4;mt++) for(int nt=0;nt<2;nt++) acc[mt][nt] = vzero;
  for(int ks = 0; ks < 5; ks++){
    bf16x8 b0 = *(const bf16x8*)&gf[col*GFS + ks*32 + kq*8];
    bf16x8 b1v = *(const bf16x8*)&gf[(16+col)*GFS + ks*32 + kq*8];
    for(int mt = 0; mt < 4; mt++){
      bf16x8 a = *(const bf16x8*)(keyP + (size_t)(ro + mt*16 + col)*KP + ks*32 + kq*8);
      acc[mt][0] = MFMA(a, b0, acc[mt][0]);
      acc[mt][1] = MFMA(a, b1v, acc[mt][1]);
    }
  }
  // stage key TRANSPOSED buf[o][n]
  for(int mt=0;mt<4;mt++) for(int nt=0;nt<2;nt++)
    for(int r=0;r<4;r++){
      int o = ro + mt*16 + kq*4 + r;
      int n = nt*16 + col;
      buf[o*NSP + n] = f2bs(fmaxf(acc[mt][nt][r], 0.0f));
    }
  // means inline from the still-live key acc; pos recomputed from gxs; bf16 out
  for(int mt=0;mt<4;mt++){
    for(int r=0;r<4;r++){
      int o = ro + mt*16 + kq*4 + r;
      float w0 = posw[o*3+0], w1 = posw[o*3+1], w2 = posw[o*3+2];
      float sp = 0, sk = 0, spk = 0;
      for(int nt=0;nt<2;nt++){
        int n = nt*16 + col;
        float p = fmaxf(w0*gxs[n*4+0] + w1*gxs[n*4+1] + w2*gxs[n*4+2], 0.0f);
        float v = fmaxf(acc[mt][nt][r], 0.0f);
        sp += p; sk += v; spk += p*v;
      }
      for(int msk=1; msk<16; msk<<=1){
        sp += __shfl_xor(sp, msk); sk += __shfl_xor(sk, msk); spk += __shfl_xor(spk, msk);
      }
      if(col == 0){
        mPos[lq*O+o] = f2bs(sp  * 0.03125f);
        mKey[lq*O+o] = f2bs(sk  * 0.03125f);
        mPK [lq*O+o] = f2bs(spk * 0.03125f);
      }
    }
  }
  __syncthreads();
  // keyT global write: thread t streams row o=t (16 conflict-free dword LDS reads)
  {
    uint vv[16];
    #pragma unroll
    for(int j=0;j<16;j++) vv[j] = *(const uint*)&buf[t*NSP + j*2];
    uint4* dst = (uint4*)(keyT + ((size_t)lq*O + t)*NS);
    dst[0] = make_uint4(vv[0],vv[1],vv[2],vv[3]);
    dst[1] = make_uint4(vv[4],vv[5],vv[6],vv[7]);
    dst[2] = make_uint4(vv[8],vv[9],vv[10],vv[11]);
    dst[3] = make_uint4(vv[12],vv[13],vv[14],vv[15]);
  }

  // ---- v = relu(bn1(W_v1 @ gf)) ----
  for(int mt=0;mt<4;mt++) for(int nt=0;nt<2;nt++) acc[mt][nt] = vzero;
  for(int ks = 0; ks < 5; ks++){
    bf16x8 b0 = *(const bf16x8*)&gf[col*GFS + ks*32 + kq*8];
    bf16x8 b1v = *(const bf16x8*)&gf[(16+col)*GFS + ks*32 + kq*8];
    for(int mt = 0; mt < 4; mt++){
      bf16x8 a = *(const bf16x8*)(v1P + (size_t)(ro + mt*16 + col)*KP + ks*32 + kq*8);
      acc[mt][0] = MFMA(a, b0, acc[mt][0]);
      acc[mt][1] = MFMA(a, b1v, acc[mt][1]);
    }
  }
  __syncthreads();      // keyT row reads of buf complete; safe to overwrite as [n][VS]
  for(int mt=0;mt<4;mt++){
    int o0 = ro + mt*16 + kq*4;
    float gg[4], bb[4];
    for(int r=0;r<4;r++){ gg[r] = g1[o0+r]; bb[r] = b1[o0+r]; }
    for(int nt=0;nt<2;nt++){
      s16x4 pk;
      for(int r=0;r<4;r++)
        pk[r] = f2bs(fmaxf(gg[r]*(acc[mt][nt][r] * BNS) + bb[r], 0.0f));
      int n = nt*16 + col;
      *(s16x4*)&buf[n*VS + o0] = pk;
    }
  }
  __syncthreads();

  // ---- val = relu(bn2(W_v2 @ v)) ----
  for(int mt=0;mt<4;mt++) for(int nt=0;nt<2;nt++) acc[mt][nt] = vzero;
  for(int ks = 0; ks < 8; ks++){
    bf16x8 b0 = *(const bf16x8*)&buf[col*VS + ks*32 + kq*8];
    bf16x8 b1v = *(const bf16x8*)&buf[(16+col)*VS + ks*32 + kq*8];
    for(int mt = 0; mt < 4; mt++){
      bf16x8 a = *(const bf16x8*)(v2b + (size_t)(ro + mt*16 + col)*O + ks*32 + kq*8);
      acc[mt][0] = MFMA(a, b0, acc[mt][0]);
      acc[mt][1] = MFMA(a, b1v, acc[mt][1]);
    }
  }
  __syncthreads();      // v2 reads of buf complete; stage val TRANSPOSED
  for(int mt=0;mt<4;mt++){
    int o0 = ro + mt*16 + kq*4;
    float gg[4], bb[4];
    for(int r=0;r<4;r++){ gg[r] = g2[o0+r]; bb[r] = b2[o0+r]; }
    for(int nt=0;nt<2;nt++){
      int n = nt*16 + col;
      for(int r=0;r<4;r++)
        buf[(o0+r)*NSP + n] = f2bs(fmaxf(gg[r]*(acc[mt][nt][r] * BNS) + bb[r], 0.0f));
    }
  }
  __syncthreads();
  // valT global write
  {
    uint vv[16];
    #pragma unroll
    for(int j=0;j<16;j++) vv[j] = *(const uint*)&buf[t*NSP + j*2];
    uint4* dst = (uint4*)(valT + ((size_t)lq*O + t)*NS);
    dst[0] = make_uint4(vv[0],vv[1],vv[2],vv[3]);
    dst[1] = make_uint4(vv[4],vv[5],vv[6],vv[7]);
    dst[2] = make_uint4(vv[8],vv[9],vv[10],vv[11]);
    dst[3] = make_uint4(vv[12],vv[13],vv[14],vv[15]);
  }
}

// ---------------- K3: channel gates, batched MFMA, bf16 means in ----------------
__global__ __launch_bounds__(256) void k_gates(
    const short* __restrict__ mPos, const short* __restrict__ mKey,
    const short* __restrict__ mPK, const short* __restrict__ gw,
    float* __restrict__ gates)
{
  int t = threadIdx.x, w = t >> 6, l = t & 63, col = l & 15, kq = l >> 4;
  int lq0 = blockIdx.x * 16;
  const short* A  = (w < 2) ? mPos : ((w == 2) ? mKey : mPK);
  const short* Wg = gw + (size_t)w * O * O;
  f32x4 acc[16];
  const f32x4 vzero = {0.0f,0.0f,0.0f,0.0f};
  for(int i=0;i<16;i++) acc[i] = vzero;
  for(int ks = 0; ks < 8; ks++){
    bf16x8 av = *(const bf16x8*)(A + (size_t)(lq0 + col)*O + ks*32 + kq*8);
    for(int nt = 0; nt < 16; nt++){
      bf16x8 bv = *(const bf16x8*)(Wg + (size_t)(nt*16 + col)*O + ks*32 + kq*8);
      acc[nt] = MFMA(av, bv, acc[nt]);
    }
  }
  for(int nt=0;nt<16;nt++) for(int r=0;r<4;r++){
    int lqq = lq0 + kq*4 + r;
    int oo = nt*16 + col;
    gates[((size_t)lqq*4 + w)*O + oo] = 1.0f / (1.0f + expf(-acc[nt][r]));
  }
}

// ---------------- K4: per-query attention + new_features (vectorized transposed reads) ----------------
__global__ __launch_bounds__(256) void k_attn(
    const short* __restrict__ keyT, const short* __restrict__ valT,
    const float* __restrict__ gxw, const float* __restrict__ posw,
    const float* __restrict__ attw, const float* __restrict__ gates,
    float* __restrict__ outNF, int q0)
{
  int lq = blockIdx.x, q = q0 + lq, t = threadIdx.x;
  __shared__ short embL[O * NSP];      // 17408 B (bf16 emb, [o][n])
  __shared__ float attnL[H * NS];      // 512 B
  __shared__ float gxs[NS * 3];        // 384 B
  __shared__ float partial[256];       // 1024 B   total ~19.3 KB
  if(t < 96) gxs[t] = gxw[q*96 + t];
  float vc  = gates[((size_t)lq*4 + 0)*O + t];
  float qc  = gates[((size_t)lq*4 + 1)*O + t];
  float kc  = gates[((size_t)lq*4 + 2)*O + t];
  float qkc = gates[((size_t)lq*4 + 3)*O + t];
  float pw0 = posw[t*3+0], pw1 = posw[t*3+1], pw2 = posw[t*3+2];
  __syncthreads();
  float posr[NS];
  #pragma unroll
  for(int n = 0; n < NS; n++)
    posr[n] = fmaxf(pw0*gxs[n*3] + pw1*gxs[n*3+1] + pw2*gxs[n*3+2], 0.0f);
  // vectorized key read (64B contiguous per thread) -> emb bf16 -> LDS row t
  {
    const short* kp = keyT + ((size_t)lq*O + t)*NS;
    #pragma unroll
    for(int g = 0; g < 4; g++){
      bf16x8 kg = *(const bf16x8*)(kp + g*8);
      #pragma unroll
      for(int jj = 0; jj < 4; jj++){
        int n0 = g*8 + jj*2;
        float kA = bs2f(kg[jj*2]),   kB = bs2f(kg[jj*2+1]);
        float eA = posr[n0]*qc   + kA*kc + posr[n0]*kA*qkc;
        float eB = posr[n0+1]*qc + kB*kc + posr[n0+1]*kB*qkc;
        unsigned pk = (unsigned)(unsigned short)f2bs(eA)
                    | ((unsigned)(unsigned short)f2bs(eB) << 16);
        *(unsigned*)&embL[t*NSP + n0] = pk;     // 4B aligned (n0 even)
      }
    }
  }
  __syncthreads();
  // score partial dot: 256 threads = 2 halves x (4 h x 32 n)
  {
    int idx = t & 127, h = idx >> 5, n = idx & 31, half = t >> 7;
    const float* aw = attw + h*O + half*128;
    const short* eb = embL + (size_t)half*128*NSP + n;
    float s0=0, s1=0, s2=0, s3=0;
    for(int o = 0; o < 128; o += 4){
      s0 += aw[o+0] * bs2f(eb[(o+0)*NSP]);
      s1 += aw[o+1] * bs2f(eb[(o+1)*NSP]);
      s2 += aw[o+2] * bs2f(eb[(o+2)*NSP]);
      s3 += aw[o+3] * bs2f(eb[(o+3)*NSP]);
    }
    partial[t] = (s0 + s1) + (s2 + s3);
  }
  __syncthreads();
  if(t < 128){
    int h = t >> 5, n = t & 31;
    float s = partial[t] + partial[t + 128];
    float mx = s;
    for(int msk=1; msk<32; msk<<=1) mx = fmaxf(mx, __shfl_xor(mx, msk));
    float e = expf(s - mx);
    float sum = e;
    for(int msk=1; msk<32; msk<<=1) sum += __shfl_xor(sum, msk);
    attnL[h*NS + n] = e / sum;
  }
  __syncthreads();
  // nf: vectorized val read (64B contiguous per thread)
  {
    const short* vp = valT + ((size_t)lq*O + t)*NS;
    int hh = t >> 6;
    float nf = 0;
    #pragma unroll
    for(int g = 0; g < 4; g++){
      bf16x8 vg = *(const bf16x8*)(vp + g*8);
      #pragma unroll
      for(int j = 0; j < 8; j++){
        int n = g*8 + j;
        nf += (bs2f(vg[j]) + posr[n]*vc) * attnL[hh*NS + n];
      }
    }
    outNF[(size_t)q*O + t] = nf;
  }
}

// ---------------- K5: cls/reg gating MLPs (64 queries/block) ----------------
__global__ __launch_bounds__(256) void k_fgate(
    const float* __restrict__ nf,            // = outNF (written by k_attn this launch)
    const short* __restrict__ cw1b, const float* __restrict__ cb1,
    const float* __restrict__ cw2, const float* __restrict__ cb2,
    const short* __restrict__ rw1b, const float* __restrict__ rb1,
    const float* __restrict__ rw2, const float* __restrict__ rb2,
    float* __restrict__ outC, float* __restrict__ outR)
{
  int t = threadIdx.x, w = t >> 6, l = t & 63, col = l & 15, kq = l >> 4;
  int q0 = blockIdx.x * 64;
  __shared__ float sC[64], sR[64];
  f32x4 acc[16];
  const f32x4 vzero = {0.0f,0.0f,0.0f,0.0f};
  for(int i=0;i<16;i++) acc[i] = vzero;
  int arow = q0 + w*16 + col;
  for(int ks = 0; ks < 8; ks++){
    union { bf16x8 v; short e[8]; } u;
    const float* ap = nf + (size_t)arow*O + ks*32 + kq*8;
    for(int j = 0; j < 8; j++) u.e[j] = f2bs(ap[j]);
    for(int nt = 0; nt < 16; nt++){
      const short* W1 = (nt < 8) ? cw1b : rw1b;
      int j = (nt & 7)*16 + col;
      bf16x8 bv = *(const bf16x8*)(W1 + (size_t)j*O + ks*32 + kq*8);
      acc[nt] = MFMA(u.v, bv, acc[nt]);
    }
  }
  for(int r = 0; r < 4; r++){
    float pc = 0, pr = 0;
    for(int nt = 0; nt < 8; nt++){
      int j = nt*16 + col;
      pc += fmaxf(acc[nt][r] + cb1[j], 0.0f) * cw2[j];
    }
    for(int nt = 8; nt < 16; nt++){
      int j = (nt - 8)*16 + col;
      pr += fmaxf(acc[nt][r] + rb1[j], 0.0f) * rw2[j];
    }
    for(int msk=1; msk<16; msk<<=1){ pc += __shfl_xor(pc, msk); pr += __shfl_xor(pr, msk); }
    if(col == 0){
      int qq = w*16 + kq*4 + r;
      sC[qq] = 1.0f / (1.0f + expf(-(pc + cb2[0])));
      sR[qq] = 1.0f / (1.0f + expf(-(pr + rb2[0])));
    }
  }
  __syncthreads();
  // wave-parallel epilogue: each wave owns one query per iteration, f32x4 per lane
  for(int it = 0; it < 16; it++){
    int qq = it*4 + w;
    float sc = sC[qq], sr = sR[qq];
    const f32x4 nv = *(const f32x4*)(nf + (size_t)(q0 + qq)*O + l*4);
    f32x4 oc, orr;
    #pragma unroll
    for(int r=0;r<4;r++){ oc[r] = nv[r]*sc; orr[r] = nv[r]*sr; }
    *(f32x4*)(outC + (size_t)(q0 + qq)*O + l*4) = oc;
    *(f32x4*)(outR + (size_t)(q0 + qq)*O + l*4) = orr;
  }
}

extern "C" void kernel_launch(void* const* d_in, const int* in_sizes, int n_in,
                              void* d_out, int out_size, void* d_ws, size_t ws_size,
                              hipStream_t stream)
{
  const float* xyz  = (const float*)d_in[0];
  const float* nxyz = (const float*)d_in[1];
  const float* feat = (const float*)d_in[2];
  const float* posw = (const float*)d_in[3];
  const float* keyw = (const float*)d_in[4];
  const float* v1w  = (const float*)d_in[5];
  const float* bn1g = (const float*)d_in[6];
  const float* bn1b = (const float*)d_in[7];
  const float* v2w  = (const float*)d_in[8];
  const float* bn2g = (const float*)d_in[9];
  const float* bn2b = (const float*)d_in[10];
  const float* attw = (const float*)d_in[11];
  const float* kcw  = (const float*)d_in[12];
  const float* qcw  = (const float*)d_in[13];
  const float* qkcw = (const float*)d_in[14];
  const float* vcw  = (const float*)d_in[15];
  const float* cw1  = (const float*)d_in[16];
  const float* cb1  = (const float*)d_in[17];
  const float* cw2  = (const float*)d_in[18];
  const float* cb2  = (const float*)d_in[19];
  const float* rw1  = (const float*)d_in[20];
  const float* rb1  = (const float*)d_in[21];
  const float* rw2  = (const float*)d_in[22];
  const float* rb2  = (const float*)d_in[23];

  // single chunk Q=4096
  const size_t fixedB = 12000000;
  const size_t perQ   = 40960;
  int Q = 64;
  for(int cand : {4096, 2048, 1024, 512, 256, 128}){
    if(fixedB + (size_t)cand*perQ <= ws_size){ Q = cand; break; }
  }

  char* p = (char*)d_ws;
  auto alloc = [&](size_t bytes){ char* r = p; p += (bytes + 255) & ~size_t(255); return r; };
  short* fT    = (short*)alloc((size_t)NTOT*C*2);
  short* keyP  = (short*)alloc((size_t)O*KP*2);
  short* v1P   = (short*)alloc((size_t)O*KP*2);
  short* v2b   = (short*)alloc((size_t)O*O*2);
  short* gw    = (short*)alloc((size_t)4*O*O*2);
  short* cw1b  = (short*)alloc((size_t)(O/2)*O*2);
  short* rw1b  = (short*)alloc((size_t)(O/2)*O*2);
  int*   idxw  = (int*)  alloc((size_t)M*NS*4);
  float* gxw   = (float*)alloc((size_t)M*NS*3*4);
  float* xyz4  = (float*)alloc((size_t)NTOT*4*4);
  float* nxyz4 = (float*)alloc((size_t)M*4*4);
  short* keyT  = (short*)alloc((size_t)Q*O*NS*2);
  short* valT  = (short*)alloc((size_t)Q*O*NS*2);
  short* mPos  = (short*)alloc((size_t)Q*O*2);
  short* mKey  = (short*)alloc((size_t)Q*O*2);
  short* mPK   = (short*)alloc((size_t)Q*O*2);
  float* gates = (float*)alloc((size_t)Q*4*O*4);

  float* outNF = (float*)d_out;
  float* outC  = outNF + (size_t)M*O;
  float* outR  = outC  + (size_t)M*O;

  k_prep     <<<512, 256, 0, stream>>>(feat, keyw, v1w, v2w, vcw, qcw, kcw, qkcw,
                                       cw1, rw1, xyz, nxyz,
                                       fT, keyP, v1P, v2b, gw, cw1b, rw1b, xyz4, nxyz4);
  k_ballq    <<<M,   256, 0, stream>>>(xyz4, nxyz4, idxw, gxw);
  for(int q0 = 0; q0 < M; q0 += Q){
    k_conv  <<<Q,    256, 0, stream>>>(fT, keyP, v1P, v2b,
                                       posw, bn1g, bn1b, bn2g, bn2b,
                                       idxw, gxw, keyT, valT, mPos, mKey, mPK, q0);
    k_gates <<<Q/16, 256, 0, stream>>>(mPos, mKey, mPK, gw, gates);
    k_attn  <<<Q,    256, 0, stream>>>(keyT, valT, gxw, posw, attw, gates, outNF, q0);
  }
  k_fgate   <<<M/64, 256, 0, stream>>>(outNF, cw1b, cb1, cw2, cb2, rw1b, rb1, rw2, rb2, outC, outR);
}